// Round 15
// baseline (670.886 us; speedup 1.0000x reference)
//
#include <hip/hip_runtime.h>
#include <hip/hip_fp16.h>
#include <hip/hip_cooperative_groups.h>
#include <math.h>

namespace cg = cooperative_groups;

// LinearCaps2d, BATCH=256, N = B_TYPES*H*W = 2048, C=10, POSE=16, 3 routing iters.
// R28: fuse R20's EXACT pass body (the proven 46.9us/pass config) into one
// cooperative kernel. Evidence: R26 halved bytes -> time unchanged (~45us floor
// is latency-structural, not bytes); every intra-pass lever is now ablated-null.
// Remaining addressable cost: ~55us (27%) of inter-kernel launch gaps.
// Prior fusion failures had identified causes, both avoided here:
//   R17: wrong geometry (1 blk/CU, 512 thr, new LDS conflicts) -> keep R20's
//        512 x 256, 45568 B LDS, WS_ROW=28, exactly 2 blocks/CU;
//   R19: launch-bounds spill (512,4)->64 regs -> keep (256,2)->128 proven.
// Correctness pattern (atomics + __threadfence + grid.sync + plain reads)
// passed the checker in both R17 and R19.
// Fallback if coop launch rejected: R20 3-kernel sequence verbatim (201.5us).
// ws: s0,s1,s2 [40960] f32.

typedef _Float16 f16;
typedef _Float16 f16x2 __attribute__((ext_vector_type(2)));
typedef _Float16 f16x4 __attribute__((ext_vector_type(4)));
typedef __fp16   h16x2 __attribute__((ext_vector_type(2)));
typedef float f32x4 __attribute__((ext_vector_type(4)));

__device__ __forceinline__ f16x2 pk(float a, float b) {
    h16x2 t = __builtin_amdgcn_cvt_pkrtz(a, b);
    return __builtin_bit_cast(f16x2, t);
}

#if __has_builtin(__builtin_amdgcn_fdot2)
__device__ __forceinline__ float FDOT2(f16x2 a, f16x2 b, float c) {
    return __builtin_amdgcn_fdot2(__builtin_bit_cast(h16x2, a),
                                  __builtin_bit_cast(h16x2, b), c, false);
}
#else
__device__ __forceinline__ float FDOT2(f16x2 a, f16x2 b, float c) {
    return c + (float)a[0] * (float)b[0] + (float)a[1] * (float)b[1];
}
#endif

constexpr int WS_ROW = 28;   // f16 row stride (16 i + 12 pad) -- R7's low-conflict value
constexpr int XS_ROW = 76;   // f16 row stride (4n x 16 i + pad)

__device__ __forceinline__ float xorsum4(float v) {
    v += __shfl_xor(v, 16, 64);
    v += __shfl_xor(v, 32, 64);
    return v;
}

// packed f16x2 cross-quad reduction: one shfl pair for two c's (verified R11)
__device__ __forceinline__ f16x2 xorsum4h(f16x2 v) {
    union { f16x2 h; int i; } u;
    union { int i; f16x2 h; } w;
    u.h = v; w.i = __shfl_xor(u.i, 16, 64); v = v + w.h;
    u.h = v; w.i = __shfl_xor(u.i, 32, 64); v = v + w.h;
    return v;
}

__device__ __forceinline__ f16x4 cvt4(float4 w) {
    f16x2 a = pk(w.x, w.y);
    f16x2 b = pk(w.z, w.w);
    f16x4 r; r[0] = a[0]; r[1] = a[1]; r[2] = b[0]; r[3] = b[1];
    return r;
}

// ================= R20 pass body as a macro-free device routine ==============
// PASS is runtime here (fused) / compile-time in the fallback template; the
// body is IDENTICAL source in both instantiations.
template<bool FUSED>
__device__ __forceinline__ void pass_body(
    int pass,
    const float* __restrict__ poses, const float* __restrict__ weight,
    const float* __restrict__ bias,
    const float* __restrict__ sp0, const float* __restrict__ sp1,
    float* __restrict__ s_dst,
    f16* Ws, f16* xs)
{
    const int tid  = threadIdx.x;
    const int blk  = blockIdx.x;
    const int ngrp = blk >> 2;          // 128 n-groups (16 n each)
    const int b0   = (blk & 3) * 64;    // 4 b-groups
    const int wave = tid >> 6;
    const int lane = tid & 63;
    const int q    = lane >> 4;
    const int lo   = lane & 15;
    const int wtb  = wave * 16;
    const int bg   = b0 + wtb;          // wave's global batch base

    // ---- staging registers + loaders (issue-early hoist, R20-verified).
    float4 wreg[10];
    float4 xreg[4];
    const int b_loc = tid >> 2, part = tid & 3;

    auto load_w = [&](int l) {
        const float* wp = weight + (size_t)(ngrp * 4 + l) * 10240;   // 4n x 160 x 16
        #pragma unroll
        for (int k = 0; k < 10; ++k) wreg[k] = ((const float4*)wp)[tid + k * 256];
    };
    auto load_x = [&](int l) {
        const float* xp = poses + (size_t)(b0 + b_loc) * 32768
                          + (size_t)(ngrp * 16 + l * 4 + part) * 16;
        #pragma unroll
        for (int j = 0; j < 4; ++j) xreg[j] = ((const float4*)xp)[j];
    };
    auto store_iter = [&]() {
        #pragma unroll
        for (int k = 0; k < 10; ++k) {
            const int f = tid + k * 256;          // float4 index in [0,2560)
            *(f16x4*)&Ws[(f >> 2) * WS_ROW + (f & 3) * 4] = cvt4(wreg[k]);
        }
        f16* lp = xs + b_loc * XS_ROW + part * 16;
        #pragma unroll
        for (int j = 0; j < 4; ++j) *(f16x4*)&lp[j * 4] = cvt4(xreg[j]);
    };

    // hoist: issue tile-0 weight loads first; latency hides under vsp preamble.
    load_w(0);

    // ---- inline squash: vsp[c] = v[b=bg+lo][c][o=q*4..q*4+3], packed f16
    f16x2 vsp[10][2];
    if (pass >= 1) {
        const int rowb = (bg + lo) * 10;
        #pragma unroll
        for (int c = 0; c < 10; ++c) {
            float4 bb = *(const float4*)(bias + c * 16 + q * 4);
            float4 sa = *(const float4*)(sp0 + (size_t)(rowb + c) * 16 + q * 4);
            float t0 = sa.x + bb.x, t1 = sa.y + bb.y, t2 = sa.z + bb.z, t3 = sa.w + bb.w;
            float n2 = xorsum4(t0*t0 + t1*t1 + t2*t2 + t3*t3);
            float sc = n2 / (1.f + n2) * rsqrtf(n2 + 1e-8f);
            float v0 = sc*t0, v1 = sc*t1, v2 = sc*t2, v3 = sc*t3;
            if (pass == 2) {
                float4 sb = *(const float4*)(sp1 + (size_t)(rowb + c) * 16 + q * 4);
                float u0 = sb.x + bb.x, u1 = sb.y + bb.y, u2 = sb.z + bb.z, u3 = sb.w + bb.w;
                float m2 = xorsum4(u0*u0 + u1*u1 + u2*u2 + u3*u3);
                float sc2 = m2 / (1.f + m2) * rsqrtf(m2 + 1e-8f);
                v0 += sc2*u0; v1 += sc2*u1; v2 += sc2*u2; v3 += sc2*u3;
            }
            vsp[c][0] = pk(v0, v1);
            vsp[c][1] = pk(v2, v3);
        }
    }

    // pose loads for tile 0 issue after the preamble.
    load_x(0);

    f32x4 acc[10];
    #pragma unroll
    for (int c = 0; c < 10; ++c) acc[c] = (f32x4){0.f, 0.f, 0.f, 0.f};

    for (int l = 0; l < 4; ++l) {
        __syncthreads();
        store_iter();
        if (l + 1 < 4) { load_w(l + 1); load_x(l + 1); }
        __syncthreads();

        #pragma unroll
        for (int n = 0; n < 4; ++n) {
            // votes^T fragments V[c][r] = votes[b=bg+lo][c][o=q*4+r] (R7 layout),
            // packed to f16 immediately to keep register pressure low.
            f16x4 bx = *(const f16x4*)&xs[(wtb + lo) * XS_ROW + n * 16 + q * 4];
            f16x2 Vh[10][2];
            #pragma unroll
            for (int c = 0; c < 10; ++c) {
                f16x4 aw = *(const f16x4*)&Ws[((n * 10 + c) * 16 + lo) * WS_ROW + q * 4];
                f32x4 V = __builtin_amdgcn_mfma_f32_16x16x16f16(
                    aw, bx, (f32x4){0.f, 0.f, 0.f, 0.f}, 0, 0, 0);
                Vh[c][0] = pk(V[0], V[1]);
                Vh[c][1] = pk(V[2], V[3]);
            }

            float cfv[10];
            if (pass >= 1) {
                // logits: fdot2 on packed votes vs vsp; packed cross-quad reduce
                float lg[10];
                #pragma unroll
                for (int cp = 0; cp < 5; ++cp) {
                    const int c0 = cp * 2, c1 = cp * 2 + 1;
                    float p0 = FDOT2(Vh[c0][0], vsp[c0][0], 0.f);
                    p0 = FDOT2(Vh[c0][1], vsp[c0][1], p0);
                    float p1 = FDOT2(Vh[c1][0], vsp[c1][0], 0.f);
                    p1 = FDOT2(Vh[c1][1], vsp[c1][1], p1);
                    f16x2 pr = xorsum4h(pk(p0, p1));
                    lg[c0] = (float)pr[0];
                    lg[c1] = (float)pr[1];
                }
                float m = lg[0];
                #pragma unroll
                for (int c = 1; c < 10; ++c) m = fmaxf(m, lg[c]);
                float sum = 0.f;
                #pragma unroll
                for (int c = 0; c < 10; ++c) { lg[c] = __expf(lg[c] - m); sum += lg[c]; }
                const float inv = 1.f / sum;
                #pragma unroll
                for (int c = 0; c < 10; ++c) cfv[c] = lg[c] * inv;
            }

            // s-accumulate straight from packed votes
            #pragma unroll
            for (int c = 0; c < 10; ++c) {
                const float w = (pass == 0) ? 1.f : cfv[c];
                acc[c][0] = fmaf(w, (float)Vh[c][0][0], acc[c][0]);
                acc[c][1] = fmaf(w, (float)Vh[c][0][1], acc[c][1]);
                acc[c][2] = fmaf(w, (float)Vh[c][1][0], acc[c][2]);
                acc[c][3] = fmaf(w, (float)Vh[c][1][1], acc[c][3]);
            }
        }
    }

    // ---- wave-local LDS transpose (b<->o) + full-line atomic flush.
    __syncthreads();                        // all waves done reading Ws/xs as f16
    float* tr = (float*)Ws + wave * 320;    // 320 floats/wave, stride-20 rows
    const float fs = (pass == 0) ? 0.1f : 1.f;
    #pragma unroll
    for (int c = 0; c < 10; ++c) {
        // write own (b=lo, o=q*4..q*4+3); 16B-aligned b128
        *(float4*)&tr[lo * 20 + q * 4] = (float4){acc[c][0], acc[c][1], acc[c][2], acc[c][3]};
        // read (b=q*4+r, o=lo) -- wave-synchronous, in-order DS ops
        float r0 = tr[(q * 4 + 0) * 20 + lo];
        float r1 = tr[(q * 4 + 1) * 20 + lo];
        float r2 = tr[(q * 4 + 2) * 20 + lo];
        float r3 = tr[(q * 4 + 3) * 20 + lo];
        float* sp = s_dst + ((size_t)(bg + q * 4) * 10 + c) * 16 + lo;
        unsafeAtomicAdd(sp + 0 * 160, fs * r0);
        unsafeAtomicAdd(sp + 1 * 160, fs * r1);
        unsafeAtomicAdd(sp + 2 * 160, fs * r2);
        unsafeAtomicAdd(sp + 3 * 160, fs * r3);
    }
}

// ---- fused cooperative kernel: 3 passes + epilogue, one dispatch.
__global__ __launch_bounds__(256, 2)
void fused_k(const float* __restrict__ poses, const float* __restrict__ weight,
             const float* __restrict__ bias,
             float* __restrict__ s0, float* __restrict__ s1,
             float* __restrict__ s2, float* __restrict__ out)
{
    __shared__ f16 Ws[640 * WS_ROW];   // 35840 B
    __shared__ f16 xs[64 * XS_ROW];    //  9728 B

    cg::grid_group grid = cg::this_grid();

    #pragma unroll 1
    for (int pass = 0; pass < 3; ++pass) {
        float* dst = (pass == 0) ? s0 : (pass == 1) ? s1 : s2;
        pass_body<true>(pass, poses, weight, bias, s0, s1, dst, Ws, xs);
        __threadfence();
        grid.sync();
    }

    // epilogue squash: 2560 rows, one (b,c) per thread (blocks 0-9).
    const int t = blockIdx.x * 256 + threadIdx.x;
    if (t < 2560) {
        const int c = t % 10;
        const float* sp = s2 + (size_t)t * 16;
        const float* bp = bias + c * 16;
        float sv[16];
        float n2 = 0.f;
        #pragma unroll
        for (int o = 0; o < 16; ++o) { float v = sp[o] + bp[o]; sv[o] = v; n2 += v * v; }
        const float scale = n2 / (1.f + n2) * rsqrtf(n2 + 1e-8f);
        float a2 = 0.f;
        #pragma unroll
        for (int o = 0; o < 16; ++o) {
            float v = scale * sv[o];
            out[(size_t)t * 16 + o] = v;
            a2 += v * v;
        }
        out[40960 + t] = sqrtf(a2 + 1e-8f);
    }
}

// ---- fallback: R20 3-kernel sequence (proven 201.5us).
template<int PASS>
__global__ __launch_bounds__(256, 2)
void pass_k(const float* __restrict__ poses, const float* __restrict__ weight,
            const float* __restrict__ bias,
            const float* __restrict__ sp0, const float* __restrict__ sp1,
            float* __restrict__ s_dst)
{
    __shared__ f16 Ws[640 * WS_ROW];
    __shared__ f16 xs[64 * XS_ROW];
    pass_body<false>(PASS, poses, weight, bias, sp0, sp1, s_dst, Ws, xs);
}

__global__ __launch_bounds__(256)
void epi_k(const float* __restrict__ s2, const float* __restrict__ bias,
           float* __restrict__ out)
{
    const int t = blockIdx.x * 256 + threadIdx.x;
    if (t >= 2560) return;
    const int c = t % 10;
    const float* sp = s2 + (size_t)t * 16;
    const float* bp = bias + c * 16;
    float sv[16];
    float n2 = 0.f;
    #pragma unroll
    for (int o = 0; o < 16; ++o) { float v = sp[o] + bp[o]; sv[o] = v; n2 += v * v; }
    const float scale = n2 / (1.f + n2) * rsqrtf(n2 + 1e-8f);
    float a2 = 0.f;
    #pragma unroll
    for (int o = 0; o < 16; ++o) {
        float v = scale * sv[o];
        out[(size_t)t * 16 + o] = v;
        a2 += v * v;
    }
    out[40960 + t] = sqrtf(a2 + 1e-8f);
}

extern "C" void kernel_launch(void* const* d_in, const int* in_sizes, int n_in,
                              void* d_out, int out_size, void* d_ws, size_t ws_size,
                              hipStream_t stream)
{
    const float* poses  = (const float*)d_in[0];
    // d_in[1] (input_caps_activations) unused by the reference.
    const float* weight = (const float*)d_in[2];
    const float* bias   = (const float*)d_in[3];
    float* out = (float*)d_out;
    float* s0 = (float*)d_ws;
    float* s1 = s0 + 40960;
    float* s2 = s1 + 40960;

    (void)hipMemsetAsync(d_ws, 0, 3 * 40960 * sizeof(float), stream);

    void* args[] = {(void*)&poses, (void*)&weight, (void*)&bias,
                    (void*)&s0, (void*)&s1, (void*)&s2, (void*)&out};
    hipError_t err = hipLaunchCooperativeKernel((const void*)fused_k,
                                                dim3(512), dim3(256),
                                                args, 0, stream);
    if (err != hipSuccess) {
        pass_k<0><<<512, 256, 0, stream>>>(poses, weight, bias, nullptr, nullptr, s0);
        pass_k<1><<<512, 256, 0, stream>>>(poses, weight, bias, s0, nullptr, s1);
        pass_k<2><<<512, 256, 0, stream>>>(poses, weight, bias, s0, s1, s2);
        epi_k<<<10, 256, 0, stream>>>(s2, bias, out);
    }
}

// Round 16
// 211.678 us; speedup vs baseline: 3.1694x; 3.1694x over previous
//
#include <hip/hip_runtime.h>
#include <hip/hip_fp16.h>
#include <math.h>

// LinearCaps2d, BATCH=256, N = B_TYPES*H*W = 2048, C=10, POSE=16, 3 routing iters.
// R29 = R20's exact body at HALF the block count: 256 blocks x 512 thr.
// Session law (3x reproduced): per-pass time tracks BLOCK COUNT at fixed total
// work (512 blk -> 47us, 1024 blk -> 65us) -- consistent with ~30 blocks/us
// dispatch ramp as the per-pass fixed cost. Never probed below 512 blocks.
//   * 256 blocks = 128 ngrp x 2 b-groups; 8 waves/block, wave w owns b-range
//     b0 + w*16 (same 16-b wave granularity as R20);
//   * weight re-staging HALVES (b-split 4 -> 2): FETCH ~58 -> ~45 MB;
//   * residency 1 blk/CU x 8 waves = 2 waves/SIMD (exactly R20's);
//   * __launch_bounds__(512,1): usage-driven regalloc (R23-proven no-spill
//     form); per-thread staging drops to 5 wreg float4 (was 10);
//   * LDS 55296 B (Ws 35840 + xs 128x76x2); transpose scratch = Ws (10240 B
//     for 8 waves, after final barrier).
// Fusion closed (R17/R19/R28: grid.sync drains L2 cross-XCD, 586us+31ms).
// Tripwires: WRITE > 35 MB = spill -> revert R20; pass >= 46us = law dead,
// conclude R20 next round. ws: s0,s1,s2 [40960] f32.

typedef _Float16 f16;
typedef _Float16 f16x2 __attribute__((ext_vector_type(2)));
typedef _Float16 f16x4 __attribute__((ext_vector_type(4)));
typedef __fp16   h16x2 __attribute__((ext_vector_type(2)));
typedef float f32x4 __attribute__((ext_vector_type(4)));

__device__ __forceinline__ f16x2 pk(float a, float b) {
    h16x2 t = __builtin_amdgcn_cvt_pkrtz(a, b);
    return __builtin_bit_cast(f16x2, t);
}

#if __has_builtin(__builtin_amdgcn_fdot2)
__device__ __forceinline__ float FDOT2(f16x2 a, f16x2 b, float c) {
    return __builtin_amdgcn_fdot2(__builtin_bit_cast(h16x2, a),
                                  __builtin_bit_cast(h16x2, b), c, false);
}
#else
__device__ __forceinline__ float FDOT2(f16x2 a, f16x2 b, float c) {
    return c + (float)a[0] * (float)b[0] + (float)a[1] * (float)b[1];
}
#endif

constexpr int WS_ROW = 28;   // f16 row stride (16 i + 12 pad) -- R7's low-conflict value
constexpr int XS_ROW = 76;   // f16 row stride (4n x 16 i + pad)

__device__ __forceinline__ float xorsum4(float v) {
    v += __shfl_xor(v, 16, 64);
    v += __shfl_xor(v, 32, 64);
    return v;
}

// packed f16x2 cross-quad reduction: one shfl pair for two c's (verified R11)
__device__ __forceinline__ f16x2 xorsum4h(f16x2 v) {
    union { f16x2 h; int i; } u;
    union { int i; f16x2 h; } w;
    u.h = v; w.i = __shfl_xor(u.i, 16, 64); v = v + w.h;
    u.h = v; w.i = __shfl_xor(u.i, 32, 64); v = v + w.h;
    return v;
}

__device__ __forceinline__ f16x4 cvt4(float4 w) {
    f16x2 a = pk(w.x, w.y);
    f16x2 b = pk(w.z, w.w);
    f16x4 r; r[0] = a[0]; r[1] = a[1]; r[2] = b[0]; r[3] = b[1];
    return r;
}

// grid: 256 blocks = 128 n-groups (16 n) x 2 b-groups (128 b); 512 thr = 8 waves.
template<int PASS>
__global__ __launch_bounds__(512, 1)
void pass_k(const float* __restrict__ poses, const float* __restrict__ weight,
            const float* __restrict__ bias,
            const float* __restrict__ sp0, const float* __restrict__ sp1,
            float* __restrict__ s_dst)
{
    __shared__ f16 Ws[640 * WS_ROW];    // 35840 B (reused as transpose buffer at end)
    __shared__ f16 xs[128 * XS_ROW];    // 19456 B: 128 b x (4n x 16 i)

    const int tid  = threadIdx.x;
    const int blk  = blockIdx.x;
    const int ngrp = blk >> 1;          // 128 n-groups (16 n each)
    const int b0   = (blk & 1) * 128;   // 2 b-groups
    const int wave = tid >> 6;
    const int lane = tid & 63;
    const int q    = lane >> 4;
    const int lo   = lane & 15;
    const int wtb  = wave * 16;
    const int bg   = b0 + wtb;          // wave's global batch base (8 waves x 16 b)

    // ---- staging registers + loaders (issue-early hoist, R20-verified order).
    float4 wreg[5];                     // 5 float4/thread (512 thr x 5 = 2560)
    float4 xreg[4];
    const int b_loc = tid >> 2, part = tid & 3;   // b_loc in [0,128)

    auto load_w = [&](int l) {
        const float* wp = weight + (size_t)(ngrp * 4 + l) * 10240;   // 4n x 160 x 16
        #pragma unroll
        for (int k = 0; k < 5; ++k) wreg[k] = ((const float4*)wp)[tid + k * 512];
    };
    auto load_x = [&](int l) {
        const float* xp = poses + (size_t)(b0 + b_loc) * 32768
                          + (size_t)(ngrp * 16 + l * 4 + part) * 16;
        #pragma unroll
        for (int j = 0; j < 4; ++j) xreg[j] = ((const float4*)xp)[j];
    };
    auto store_iter = [&]() {
        #pragma unroll
        for (int k = 0; k < 5; ++k) {
            const int f = tid + k * 512;          // float4 index in [0,2560)
            *(f16x4*)&Ws[(f >> 2) * WS_ROW + (f & 3) * 4] = cvt4(wreg[k]);
        }
        f16* lp = xs + b_loc * XS_ROW + part * 16;
        #pragma unroll
        for (int j = 0; j < 4; ++j) *(f16x4*)&lp[j * 4] = cvt4(xreg[j]);
    };

    // hoist: issue tile-0 weight loads first; latency hides under vsp preamble.
    load_w(0);

    // ---- inline squash: vsp[c] = v[b=bg+lo][c][o=q*4..q*4+3], packed f16
    f16x2 vsp[10][2];
    if (PASS >= 1) {
        const int rowb = (bg + lo) * 10;
        #pragma unroll
        for (int c = 0; c < 10; ++c) {
            float4 bb = *(const float4*)(bias + c * 16 + q * 4);
            float4 sa = *(const float4*)(sp0 + (size_t)(rowb + c) * 16 + q * 4);
            float t0 = sa.x + bb.x, t1 = sa.y + bb.y, t2 = sa.z + bb.z, t3 = sa.w + bb.w;
            float n2 = xorsum4(t0*t0 + t1*t1 + t2*t2 + t3*t3);
            float sc = n2 / (1.f + n2) * rsqrtf(n2 + 1e-8f);
            float v0 = sc*t0, v1 = sc*t1, v2 = sc*t2, v3 = sc*t3;
            if (PASS == 2) {
                float4 sb = *(const float4*)(sp1 + (size_t)(rowb + c) * 16 + q * 4);
                float u0 = sb.x + bb.x, u1 = sb.y + bb.y, u2 = sb.z + bb.z, u3 = sb.w + bb.w;
                float m2 = xorsum4(u0*u0 + u1*u1 + u2*u2 + u3*u3);
                float sc2 = m2 / (1.f + m2) * rsqrtf(m2 + 1e-8f);
                v0 += sc2*u0; v1 += sc2*u1; v2 += sc2*u2; v3 += sc2*u3;
            }
            vsp[c][0] = pk(v0, v1);
            vsp[c][1] = pk(v2, v3);
        }
    }

    // pose loads for tile 0 issue after the preamble.
    load_x(0);

    f32x4 acc[10];
    #pragma unroll
    for (int c = 0; c < 10; ++c) acc[c] = (f32x4){0.f, 0.f, 0.f, 0.f};

    for (int l = 0; l < 4; ++l) {
        __syncthreads();
        store_iter();
        if (l + 1 < 4) { load_w(l + 1); load_x(l + 1); }
        __syncthreads();

        #pragma unroll
        for (int n = 0; n < 4; ++n) {
            // votes^T fragments V[c][r] = votes[b=bg+lo][c][o=q*4+r] (R7 layout),
            // packed to f16 immediately to keep register pressure low.
            f16x4 bx = *(const f16x4*)&xs[(wtb + lo) * XS_ROW + n * 16 + q * 4];
            f16x2 Vh[10][2];
            #pragma unroll
            for (int c = 0; c < 10; ++c) {
                f16x4 aw = *(const f16x4*)&Ws[((n * 10 + c) * 16 + lo) * WS_ROW + q * 4];
                f32x4 V = __builtin_amdgcn_mfma_f32_16x16x16f16(
                    aw, bx, (f32x4){0.f, 0.f, 0.f, 0.f}, 0, 0, 0);
                Vh[c][0] = pk(V[0], V[1]);
                Vh[c][1] = pk(V[2], V[3]);
            }

            float cfv[10];
            if (PASS >= 1) {
                // logits: fdot2 on packed votes vs vsp; packed cross-quad reduce
                float lg[10];
                #pragma unroll
                for (int cp = 0; cp < 5; ++cp) {
                    const int c0 = cp * 2, c1 = cp * 2 + 1;
                    float p0 = FDOT2(Vh[c0][0], vsp[c0][0], 0.f);
                    p0 = FDOT2(Vh[c0][1], vsp[c0][1], p0);
                    float p1 = FDOT2(Vh[c1][0], vsp[c1][0], 0.f);
                    p1 = FDOT2(Vh[c1][1], vsp[c1][1], p1);
                    f16x2 pr = xorsum4h(pk(p0, p1));
                    lg[c0] = (float)pr[0];
                    lg[c1] = (float)pr[1];
                }
                float m = lg[0];
                #pragma unroll
                for (int c = 1; c < 10; ++c) m = fmaxf(m, lg[c]);
                float sum = 0.f;
                #pragma unroll
                for (int c = 0; c < 10; ++c) { lg[c] = __expf(lg[c] - m); sum += lg[c]; }
                const float inv = 1.f / sum;
                #pragma unroll
                for (int c = 0; c < 10; ++c) cfv[c] = lg[c] * inv;
            }

            // s-accumulate straight from packed votes
            #pragma unroll
            for (int c = 0; c < 10; ++c) {
                const float w = (PASS == 0) ? 1.f : cfv[c];
                acc[c][0] = fmaf(w, (float)Vh[c][0][0], acc[c][0]);
                acc[c][1] = fmaf(w, (float)Vh[c][0][1], acc[c][1]);
                acc[c][2] = fmaf(w, (float)Vh[c][1][0], acc[c][2]);
                acc[c][3] = fmaf(w, (float)Vh[c][1][1], acc[c][3]);
            }
        }
    }

    // ---- wave-local LDS transpose (b<->o) + full-line atomic flush.
    __syncthreads();                        // all waves done reading Ws/xs as f16
    float* tr = (float*)Ws + wave * 320;    // 8 waves x 320 floats = 10240 B
    const float fs = (PASS == 0) ? 0.1f : 1.f;
    #pragma unroll
    for (int c = 0; c < 10; ++c) {
        // write own (b=lo, o=q*4..q*4+3); 16B-aligned b128
        *(float4*)&tr[lo * 20 + q * 4] = (float4){acc[c][0], acc[c][1], acc[c][2], acc[c][3]};
        // read (b=q*4+r, o=lo) -- wave-synchronous, in-order DS ops
        float r0 = tr[(q * 4 + 0) * 20 + lo];
        float r1 = tr[(q * 4 + 1) * 20 + lo];
        float r2 = tr[(q * 4 + 2) * 20 + lo];
        float r3 = tr[(q * 4 + 3) * 20 + lo];
        float* sp = s_dst + ((size_t)(bg + q * 4) * 10 + c) * 16 + lo;
        unsafeAtomicAdd(sp + 0 * 160, fs * r0);
        unsafeAtomicAdd(sp + 1 * 160, fs * r1);
        unsafeAtomicAdd(sp + 2 * 160, fs * r2);
        unsafeAtomicAdd(sp + 3 * 160, fs * r3);
    }
}

// final squash: 2560 rows, one (b,c) per thread (verified R3/R7).
__global__ __launch_bounds__(256)
void epi_k(const float* __restrict__ s2, const float* __restrict__ bias,
           float* __restrict__ out)
{
    const int t = blockIdx.x * 256 + threadIdx.x;
    if (t >= 2560) return;
    const int c = t % 10;
    const float* sp = s2 + (size_t)t * 16;
    const float* bp = bias + c * 16;
    float sv[16];
    float n2 = 0.f;
    #pragma unroll
    for (int o = 0; o < 16; ++o) { float v = sp[o] + bp[o]; sv[o] = v; n2 += v * v; }
    const float scale = n2 / (1.f + n2) * rsqrtf(n2 + 1e-8f);
    float a2 = 0.f;
    #pragma unroll
    for (int o = 0; o < 16; ++o) {
        float v = scale * sv[o];
        out[(size_t)t * 16 + o] = v;
        a2 += v * v;
    }
    out[40960 + t] = sqrtf(a2 + 1e-8f);
}

extern "C" void kernel_launch(void* const* d_in, const int* in_sizes, int n_in,
                              void* d_out, int out_size, void* d_ws, size_t ws_size,
                              hipStream_t stream)
{
    const float* poses  = (const float*)d_in[0];
    // d_in[1] (input_caps_activations) unused by the reference.
    const float* weight = (const float*)d_in[2];
    const float* bias   = (const float*)d_in[3];
    float* out = (float*)d_out;
    float* s0 = (float*)d_ws;
    float* s1 = s0 + 40960;
    float* s2 = s1 + 40960;

    (void)hipMemsetAsync(d_ws, 0, 3 * 40960 * sizeof(float), stream);

    pass_k<0><<<256, 512, 0, stream>>>(poses, weight, bias, nullptr, nullptr, s0);
    pass_k<1><<<256, 512, 0, stream>>>(poses, weight, bias, s0, nullptr, s1);
    pass_k<2><<<256, 512, 0, stream>>>(poses, weight, bias, s0, s1, s2);
    epi_k<<<10, 256, 0, stream>>>(s2, bias, out);
}